// Round 1
// 2092.640 us; speedup vs baseline: 1.2532x; 1.2532x over previous
//
#include <hip/hip_runtime.h>
#include <hip/hip_bf16.h>

// sLSTM fused cell: B=D=4096.
// pre_g = [x, h^T] @ [w_g; u_g]  (M=4096, N=4096, K=8192), 4 gates -> 1.1 TFLOP
// GEMM rewritten to the 256^2 phased template (T1+T2+T3/T4+T5):
//   256x256 tile, BK=32, 8 waves, quad-buffered LDS (128 KB), counted vmcnt(4),
//   XOR bank-swizzle (both-sides), setprio around MFMA, bijective XCD swizzle.

#define DD 4096
#define BB 4096
#define KK 8192   // 2*DD

typedef __hip_bfloat16 bf16;
typedef __attribute__((ext_vector_type(8))) short short8;
typedef __attribute__((ext_vector_type(4))) float f32x4;

__device__ __forceinline__ void gld_lds16(const bf16* g, bf16* l) {
    __builtin_amdgcn_global_load_lds(
        (const __attribute__((address_space(1))) void*)g,
        (__attribute__((address_space(3))) void*)l,
        16, 0, 0);
}

// ---- cast x (4096x4096 f32, row-major) into Ahat[b][0..4095], row stride KK ----
__global__ __launch_bounds__(256) void cast_x(const float* __restrict__ x,
                                              bf16* __restrict__ A) {
    long base = ((long)blockIdx.x * 256 + threadIdx.x) * 4;
    int b = (int)(base >> 12);
    int k = (int)(base & 4095);
    float4 v = *(const float4*)(x + base);
    bf16 tmp[4];
    tmp[0] = __float2bfloat16(v.x);
    tmp[1] = __float2bfloat16(v.y);
    tmp[2] = __float2bfloat16(v.z);
    tmp[3] = __float2bfloat16(v.w);
    bf16* o = A + (long)b * KK + k;
    *(uint2*)o = *(uint2*)tmp;  // 8B store, aligned (k%4==0)
}

// ---- transpose-cast: out[c * KK + outOff + r] = bf16(in[r * 4096 + c]) ----
__global__ __launch_bounds__(256) void transpose_cast(const float* __restrict__ in,
                                                      bf16* __restrict__ out,
                                                      long outOff) {
    __shared__ float tile[32][33];
    int r0 = blockIdx.y * 32;
    int c0 = blockIdx.x * 32;
    int tx = threadIdx.x;  // 0..31
    int ty = threadIdx.y;  // 0..7
    #pragma unroll
    for (int i = 0; i < 4; i++) {
        int r = r0 + ty + i * 8;
        tile[ty + i * 8][tx] = in[(long)r * 4096 + c0 + tx];
    }
    __syncthreads();
    #pragma unroll
    for (int i = 0; i < 4; i++) {
        int c = c0 + ty + i * 8;
        out[(long)c * KK + outOff + r0 + tx] = __float2bfloat16(tile[tx][ty + i * 8]);
    }
}

// ======================= 256^2 phased GEMM =======================
// A: (4096 x KK) bf16 row-major.  Bt: per-gate (4096 x KK) bf16 (B^T).
// K-tile = 32. LDS tile: [256 rows][32 cols] bf16 = 16 KB per matrix,
// 4 buffers deep. Row = 64 B = 4 x 16B slots; bank swizzle:
//   colb' = colb ^ (((row>>1)&3)<<4)   (involution, in-row)
// Staging (global_load_lds, linear dest): wave w, round r -> chunk (w*2+r),
// lane l -> row = chunk*16 + l/4, colb = (l&3)*16; source column pre-swizzled.

template<int MODE>  // 0: stage next-next tile + vmcnt(4); 1: no stage + vmcnt(0); 2: plain
__device__ __forceinline__ void tile_step(
    const bf16* __restrict__ Ab, const bf16* __restrict__ Bb,
    const int (&aoff)[8], const int (&boff)[4],
    f32x4 (&acc)[8][4],
    const bf16* aS0, const bf16* aS1, const bf16* bS0, const bf16* bS1,
    bf16* dA0, bf16* dA1, bf16* dB0, bf16* dB1)
{
    short8 af[8], bfv[4];
    // ---------------- phase 1: A[0..7], B[0..1] ----------------
    #pragma unroll
    for (int i = 0; i < 8; i++) af[i] = *(const short8*)(Ab + aoff[i]);
    bfv[0] = *(const short8*)(Bb + boff[0]);
    bfv[1] = *(const short8*)(Bb + boff[1]);
    if constexpr (MODE == 0) { gld_lds16(aS0, dA0); gld_lds16(aS1, dA1); }
    __builtin_amdgcn_s_barrier();
    asm volatile("s_waitcnt lgkmcnt(0)" ::: "memory");
    __builtin_amdgcn_sched_barrier(0);
    __builtin_amdgcn_s_setprio(1);
    #pragma unroll
    for (int i = 0; i < 8; i++) {
        acc[i][0] = __builtin_amdgcn_mfma_f32_16x16x32_bf16(af[i], bfv[0], acc[i][0], 0, 0, 0);
        acc[i][1] = __builtin_amdgcn_mfma_f32_16x16x32_bf16(af[i], bfv[1], acc[i][1], 0, 0, 0);
    }
    __builtin_amdgcn_s_setprio(0);
    __builtin_amdgcn_s_barrier();
    // ---------------- phase 2: A[0..7], B[2..3] ----------------
    bfv[2] = *(const short8*)(Bb + boff[2]);
    bfv[3] = *(const short8*)(Bb + boff[3]);
    if constexpr (MODE == 0) { gld_lds16(bS0, dB0); gld_lds16(bS1, dB1); }
    if constexpr (MODE == 0) asm volatile("s_waitcnt vmcnt(4)" ::: "memory");
    if constexpr (MODE == 1) asm volatile("s_waitcnt vmcnt(0)" ::: "memory");
    __builtin_amdgcn_s_barrier();
    asm volatile("s_waitcnt lgkmcnt(0)" ::: "memory");
    __builtin_amdgcn_sched_barrier(0);
    __builtin_amdgcn_s_setprio(1);
    #pragma unroll
    for (int i = 0; i < 8; i++) {
        acc[i][2] = __builtin_amdgcn_mfma_f32_16x16x32_bf16(af[i], bfv[2], acc[i][2], 0, 0, 0);
        acc[i][3] = __builtin_amdgcn_mfma_f32_16x16x32_bf16(af[i], bfv[3], acc[i][3], 0, 0, 0);
    }
    __builtin_amdgcn_s_setprio(0);
    __builtin_amdgcn_s_barrier();
}

__global__ __launch_bounds__(512, 2) void gemm_bt8(const bf16* __restrict__ A,
                                                   const bf16* __restrict__ Bt,
                                                   float* __restrict__ C) {
    __shared__ bf16 Ash[4 * 8192];   // 4 bufs x 256x32 bf16 = 64 KB
    __shared__ bf16 Bsh[4 * 8192];   // 64 KB

    // T1: bijective XCD swizzle (nwg = 1024, divisible by 8).
    // Post-swizzle: XCD x owns wg' in [x*128, x*128+128): gate = wg'>>8,
    // n-tile = (wg'>>4)&15, m-tile fastest -> 4MB B panel resident in that L2.
    int wg = blockIdx.x;
    wg = (wg & 7) * 128 + (wg >> 3);
    const int g  = wg >> 8;
    const int n0 = ((wg >> 4) & 15) << 8;
    const int m0 = (wg & 15) << 8;

    const bf16* Bg = Bt + (long)g * DD * KK;
    float* Cg = C + (long)g * BB * DD;

    const int tid  = threadIdx.x;
    const int w    = tid >> 6;
    const int lane = tid & 63;
    const int wm   = w & 1;        // 2 wave-rows
    const int wn   = w >> 1;       // 4 wave-cols
    const int quad = lane >> 4;
    const int fr   = lane & 15;

    // staging source (pre-swizzled column; elements)
    const int srow = lane >> 2;                                     // 0..15
    const int scol = ((lane & 3) * 8) ^ (((lane >> 3) & 3) << 3);   // bf16 units
    const bf16* aS0 = A  + (long)(m0 + w * 32      + srow) * KK + scol;
    const bf16* aS1 = A  + (long)(m0 + w * 32 + 16 + srow) * KK + scol;
    const bf16* bS0 = Bg + (long)(n0 + w * 32      + srow) * KK + scol;
    const bf16* bS1 = Bg + (long)(n0 + w * 32 + 16 + srow) * KK + scol;

    const int dch = w * 1024;   // this wave's 2-chunk LDS region (elements)

    // ds_read fragment offsets (elements): row*32 + ((quad*8) ^ swz(row))
    // swz depends only on fr since row = 16*a + fr:  ((fr>>1)&3)<<3 (elements)
    const int kc = (quad * 8) ^ (((fr >> 1) & 3) << 3);
    int aoff[8], boff[4];
    #pragma unroll
    for (int i = 0; i < 8; i++) aoff[i] = (wm * 128 + i * 16 + fr) * 32 + kc;
    #pragma unroll
    for (int j = 0; j < 4; j++) boff[j] = (wn * 64 + j * 16 + fr) * 32 + kc;

    f32x4 acc[8][4];
    #pragma unroll
    for (int i = 0; i < 8; i++)
        #pragma unroll
        for (int j = 0; j < 4; j++) acc[i][j] = (f32x4){0.f, 0.f, 0.f, 0.f};

    // -------- prologue: stage tiles 0 (buf0) and 1 (buf1) --------
    gld_lds16(aS0, Ash + dch);        gld_lds16(aS1, Ash + dch + 512);
    gld_lds16(bS0, Bsh + dch);        gld_lds16(bS1, Bsh + dch + 512);
    aS0 += 32; aS1 += 32; bS0 += 32; bS1 += 32;
    gld_lds16(aS0, Ash + 8192 + dch); gld_lds16(aS1, Ash + 8192 + dch + 512);
    gld_lds16(bS0, Bsh + 8192 + dch); gld_lds16(bS1, Bsh + 8192 + dch + 512);
    aS0 += 32; aS1 += 32; bS0 += 32; bS1 += 32;
    asm volatile("s_waitcnt vmcnt(4)" ::: "memory");   // tile 0 landed; tile 1 in flight
    __builtin_amdgcn_s_barrier();

    const int NT = KK / 32;   // 256 K-tiles
    for (int tk = 0; tk < NT - 2; ++tk) {
        const int buf = (tk & 3) * 8192;
        const int sb  = ((tk + 2) & 3) * 8192;
        tile_step<0>(Ash + buf, Bsh + buf, aoff, boff, acc,
                     aS0, aS1, bS0, bS1,
                     Ash + sb + dch, Ash + sb + dch + 512,
                     Bsh + sb + dch, Bsh + sb + dch + 512);
        aS0 += 32; aS1 += 32; bS0 += 32; bS1 += 32;
    }
    {   // tk = NT-2: no stage; drain so last tile is resident
        const int buf = ((NT - 2) & 3) * 8192;
        tile_step<1>(Ash + buf, Bsh + buf, aoff, boff, acc,
                     nullptr, nullptr, nullptr, nullptr,
                     nullptr, nullptr, nullptr, nullptr);
    }
    {   // tk = NT-1
        const int buf = ((NT - 1) & 3) * 8192;
        tile_step<2>(Ash + buf, Bsh + buf, aoff, boff, acc,
                     nullptr, nullptr, nullptr, nullptr,
                     nullptr, nullptr, nullptr, nullptr);
    }

    // C/D layout (m89/m91-verified): col = lane&15, row = quad*4 + reg
    #pragma unroll
    for (int i = 0; i < 8; i++) {
        const int rbase = m0 + wm * 128 + i * 16 + quad * 4;
        #pragma unroll
        for (int j = 0; j < 4; j++) {
            const int col = n0 + wn * 64 + j * 16 + fr;
            #pragma unroll
            for (int p = 0; p < 4; p++)
                Cg[(long)(rbase + p) * DD + col] = acc[i][j][p];
        }
    }
}

// ---- elementwise epilogue: in-place on d_out (pre_i|pre_f|pre_o|pre_c -> h|c|m|n) ----
__global__ __launch_bounds__(256) void epilogue(float* __restrict__ out,
                                                const float* __restrict__ cc,
                                                const float* __restrict__ mm,
                                                const float* __restrict__ nn,
                                                const float* __restrict__ bi,
                                                const float* __restrict__ bff,
                                                const float* __restrict__ bo,
                                                const float* __restrict__ bc) {
    const long S = (long)BB * DD;
    long idx = (long)blockIdx.x * 256 + threadIdx.x;
    int j = (int)(idx & (DD - 1));
    float p_i = out[idx]         + bi[j];
    float p_f = out[S + idx]     + bff[j];
    float p_o = out[2 * S + idx] + bo[j];
    float p_c = out[3 * S + idx] + bc[j];
    float mv = mm[idx], cv = cc[idx], nv = nn[idx];

    float m_new = fmaxf(p_f + mv, p_i);
    float i_p = expf(p_i - m_new);
    float f_p = expf(p_f);   // faithful to reference: exp(log f + m - m)
    float o_t = 1.0f / (1.0f + expf(-p_o));
    float z_t = tanhf(p_c);
    float c_new = f_p * cv + i_p * z_t;
    float n_new = f_p * nv + i_p;   // n>0, f_p,i_p>0 => n_new>0
    float h_new = o_t * (c_new / n_new);

    out[idx]         = h_new;
    out[S + idx]     = c_new;
    out[2 * S + idx] = m_new;
    out[3 * S + idx] = n_new;
}

extern "C" void kernel_launch(void* const* d_in, const int* in_sizes, int n_in,
                              void* d_out, int out_size, void* d_ws, size_t ws_size,
                              hipStream_t stream) {
    const float* x  = (const float*)d_in[0];
    const float* h  = (const float*)d_in[1];
    const float* c  = (const float*)d_in[2];
    const float* m  = (const float*)d_in[3];
    const float* n  = (const float*)d_in[4];
    const float* W[4] = {(const float*)d_in[5], (const float*)d_in[6],
                         (const float*)d_in[7], (const float*)d_in[8]};
    const float* U[4] = {(const float*)d_in[9], (const float*)d_in[10],
                         (const float*)d_in[11], (const float*)d_in[12]};
    const float* bi = (const float*)d_in[13];
    const float* bf = (const float*)d_in[14];
    const float* bo = (const float*)d_in[15];
    const float* bc = (const float*)d_in[16];
    float* out = (float*)d_out;

    // Workspace layout (bf16): Ahat (BB x KK) then WT[4] (DD x KK each) = 320 MiB
    bf16* Ahat = (bf16*)d_ws;
    bf16* WT   = Ahat + (long)BB * KK;

    // 1) casts/transposes
    cast_x<<<(BB * (long)DD / 4) / 256, 256, 0, stream>>>(x, Ahat);
    dim3 tb(32, 8);
    dim3 tg(128, 128);
    transpose_cast<<<tg, tb, 0, stream>>>(h, Ahat, 4096);  // h^T -> cols 4096..
    for (int g = 0; g < 4; g++) {
        bf16* WTg = WT + (long)g * DD * KK;
        transpose_cast<<<tg, tb, 0, stream>>>(W[g], WTg, 0);
        transpose_cast<<<tg, tb, 0, stream>>>(U[g], WTg, 4096);
    }

    // 2) fused 4-gate GEMM -> pre activations into d_out (as scratch)
    gemm_bt8<<<dim3(16 * 16 * 4), 512, 0, stream>>>(Ahat, WT, out);

    // 3) elementwise sLSTM epilogue, in place
    epilogue<<<(unsigned)(((long)BB * DD) / 256), 256, 0, stream>>>(
        out, c, m, n, bi, bf, bo, bc);
}